// Round 8
// baseline (1691.063 us; speedup 1.0000x reference)
//
#include <hip/hip_runtime.h>

// Dilated conv2d as implicit GEMM, parity-ring edition, round 8.
// Root cause of rounds 4-7 (2.6-2.9 GB FETCH, VGPR capped 128, MfmaUtil 8%):
// 45 taps x 4 frags of literal A offsets spanning 184 KB exceed the 13-bit
// global-load imm, so the compiler materialized ~180 loop-invariant 64-bit
// addresses, hoisted them (LICM), and spilled the address table to scratch
// (reads >> writes: reloaded per use). Fix: ONE running A pointer advanced
// +4096 B per tap (strength-reduced, not hoistable); frag offsets 0/1024/
// 2048/3072 B fold into the load immediate. B folds into ds_read imms off
// 5 slot-base regs. A and B both ping-pong (32+32 regs). Serial staging
// phase as round 7. Live arch regs ~110 < 128.

#define CIN 32
#define HH 512
#define WW 512
#define COUT 64
#define OH 508
#define OW 496
#define KH 5
#define KW 9
#define NTAP 45

#define WTILE 128
#define SW 152              // staged width: 128 + 24 halo (origin iw = w0-4)
#define OCT_STRIDE 1224     // SW*8 + 8 elts = 2448B (16B-aligned, banks spread)
#define SLOT_STRIDE 4896    // 4 * OCT_STRIDE elts = 9792B per row-slab
#define NSLOT 8             // ring: 6 active + 2 prefetch (78336 B total)
#define NIT 304             // staging items per row: (SW/4)*8
#define STEPS 16            // 2 oh rows per step -> 32 same-parity oh per block

typedef short short8 __attribute__((ext_vector_type(8)));
typedef float floatx4 __attribute__((ext_vector_type(4)));
typedef unsigned short u16;
typedef unsigned int u32;

__device__ __forceinline__ u16 f2bf(float f) {  // RNE f32->bf16
    u32 u = __float_as_uint(f);
    return (u16)((u + 0x7fffu + ((u >> 16) & 1u)) >> 16);
}

__global__ void repack_w_k(const float* __restrict__ w, u16* __restrict__ wr) {
    int idx = blockIdx.x * 256 + threadIdx.x;
    if (idx >= NTAP * COUT * CIN) return;
    int tap = idx / (COUT * CIN);
    int rem = idx - tap * (COUT * CIN);
    int co = rem / CIN;
    int ci = rem - co * CIN;
    int r  = tap / KW;
    int kw = tap - r * KW;
    wr[idx] = f2bf(w[((co * CIN + ci) * KH + r) * KW + kw]);
}

__global__ __launch_bounds__(256, 2)
void conv_ring(const float* __restrict__ x, const u16* __restrict__ wrep,
               float* __restrict__ out) {
    __shared__ u16 s[NSLOT * SLOT_STRIDE];  // 78336 B -> 2 blocks/CU

    const int bx     = blockIdx.x;          // 0..7: wt(2b) | parity(1b)
    const int wt     = bx & 3;
    const int parity = bx >> 2;
    const int chunk  = blockIdx.y;          // 0..7
    const int b      = blockIdx.z;          // 0..7
    const int w0     = wt * WTILE;
    const int oh0    = parity + 64 * chunk;
    const int ihbase = oh0 - 2;
    const int iwbase = w0 - 4;

    const int tid  = threadIdx.x;
    const int lane = tid & 63;
    const int wave = tid >> 6;
    const int wp   = wave & 1;   // pos half (64)
    const int wo   = wave >> 1;  // which of the 2 oh rows this step
    const int li   = lane & 15;
    const int h    = lane >> 4;

    const size_t cstr = (size_t)HH * WW;    // x channel stride
    const float* xb = x + (size_t)b * CIN * cstr;

    // ---------------- prologue: stage rows j = 0..5 ----------------
    for (int it = tid; it < 6 * NIT; it += 256) {
        int j   = it / NIT;
        int rem = it - j * NIT;
        int w4  = rem >> 3;
        int q   = rem & 7;      // cin quad: cin = 4q..4q+3
        int ih  = ihbase + 2 * j;
        int iw0 = iwbase + 4 * w4;
        float4 m0 = {0,0,0,0}, m1 = {0,0,0,0}, m2 = {0,0,0,0}, m3 = {0,0,0,0};
        if ((unsigned)ih < HH && (unsigned)iw0 < WW) {
            const float* p = xb + (size_t)(4 * q) * cstr + (size_t)ih * WW + iw0;
            m0 = *(const float4*)(p);
            m1 = *(const float4*)(p + cstr);
            m2 = *(const float4*)(p + 2 * cstr);
            m3 = *(const float4*)(p + 3 * cstr);
        }
        u16* dst = s + (j & 7) * SLOT_STRIDE + (q >> 1) * OCT_STRIDE + (q & 1) * 4;
        const float* f0 = (const float*)&m0; const float* f1 = (const float*)&m1;
        const float* f2 = (const float*)&m2; const float* f3 = (const float*)&m3;
        #pragma unroll
        for (int jj = 0; jj < 4; ++jj) {
            u32 lo = (u32)f2bf(f0[jj]) | ((u32)f2bf(f1[jj]) << 16);
            u32 hi = (u32)f2bf(f2[jj]) | ((u32)f2bf(f3[jj]) << 16);
            *(uint2*)(dst + (4 * w4 + jj) * 8) = make_uint2(lo, hi);
        }
    }
    __syncthreads();

    const u16* abase0 = wrep + li * CIN + 8 * h;
    const int  bfixed = h * OCT_STRIDE + (64 * wp + li) * 8;

// A-frag load from running pointer ap_ (frag offsets 1024B -> fold into imm)
#define LOADA(A0, A1, A2, A3, ap_) do { \
        A0 = *(const short8*)((ap_) + 0 * 16 * CIN); \
        A1 = *(const short8*)((ap_) + 1 * 16 * CIN); \
        A2 = *(const short8*)((ap_) + 2 * 16 * CIN); \
        A3 = *(const short8*)((ap_) + 3 * 16 * CIN); } while (0)

// B-frag load at literal kw from per-r slot base (folds into ds_read imm)
#define LOADB(B0, B1, B2, B3, bsl, kw_) do { \
        const u16* bp_ = (bsl) + (kw_) * 24; \
        B0 = *(const short8*)(bp_ + 0 * 128); \
        B1 = *(const short8*)(bp_ + 1 * 128); \
        B2 = *(const short8*)(bp_ + 2 * 128); \
        B3 = *(const short8*)(bp_ + 3 * 128); } while (0)

#define MFMA16(A0, A1, A2, A3, B0, B1, B2, B3) do { \
        __builtin_amdgcn_s_setprio(1); \
        acc[0][0] = __builtin_amdgcn_mfma_f32_16x16x32_bf16(A0, B0, acc[0][0], 0, 0, 0); \
        acc[0][1] = __builtin_amdgcn_mfma_f32_16x16x32_bf16(A0, B1, acc[0][1], 0, 0, 0); \
        acc[0][2] = __builtin_amdgcn_mfma_f32_16x16x32_bf16(A0, B2, acc[0][2], 0, 0, 0); \
        acc[0][3] = __builtin_amdgcn_mfma_f32_16x16x32_bf16(A0, B3, acc[0][3], 0, 0, 0); \
        acc[1][0] = __builtin_amdgcn_mfma_f32_16x16x32_bf16(A1, B0, acc[1][0], 0, 0, 0); \
        acc[1][1] = __builtin_amdgcn_mfma_f32_16x16x32_bf16(A1, B1, acc[1][1], 0, 0, 0); \
        acc[1][2] = __builtin_amdgcn_mfma_f32_16x16x32_bf16(A1, B2, acc[1][2], 0, 0, 0); \
        acc[1][3] = __builtin_amdgcn_mfma_f32_16x16x32_bf16(A1, B3, acc[1][3], 0, 0, 0); \
        acc[2][0] = __builtin_amdgcn_mfma_f32_16x16x32_bf16(A2, B0, acc[2][0], 0, 0, 0); \
        acc[2][1] = __builtin_amdgcn_mfma_f32_16x16x32_bf16(A2, B1, acc[2][1], 0, 0, 0); \
        acc[2][2] = __builtin_amdgcn_mfma_f32_16x16x32_bf16(A2, B2, acc[2][2], 0, 0, 0); \
        acc[2][3] = __builtin_amdgcn_mfma_f32_16x16x32_bf16(A2, B3, acc[2][3], 0, 0, 0); \
        acc[3][0] = __builtin_amdgcn_mfma_f32_16x16x32_bf16(A3, B0, acc[3][0], 0, 0, 0); \
        acc[3][1] = __builtin_amdgcn_mfma_f32_16x16x32_bf16(A3, B1, acc[3][1], 0, 0, 0); \
        acc[3][2] = __builtin_amdgcn_mfma_f32_16x16x32_bf16(A3, B2, acc[3][2], 0, 0, 0); \
        acc[3][3] = __builtin_amdgcn_mfma_f32_16x16x32_bf16(A3, B3, acc[3][3], 0, 0, 0); \
        __builtin_amdgcn_s_setprio(0); } while (0)

// Body computing CURRENT tap from {X|Y}, prefetching NEXT tap's A (running
// pointer += 2048 elts = 4096 B) and B (literal slot/kw) into the other pair.
#define TAPX(bsl, kwn) do { \
        ap += 2048; \
        LOADA(ay0, ay1, ay2, ay3, ap); \
        LOADB(by0, by1, by2, by3, bsl, kwn); \
        MFMA16(ax0, ax1, ax2, ax3, bx0, bx1, bx2, bx3); } while (0)
#define TAPY(bsl, kwn) do { \
        ap += 2048; \
        LOADA(ax0, ax1, ax2, ax3, ap); \
        LOADB(bx0, bx1, bx2, bx3, bsl, kwn); \
        MFMA16(ay0, ay1, ay2, ay3, by0, by1, by2, by3); } while (0)

    floatx4 acc[4][4];

    #pragma unroll 1
    for (int st = 0; st < STEPS; ++st) {
        #pragma unroll
        for (int mi = 0; mi < 4; ++mi)
            #pragma unroll
            for (int ni = 0; ni < 4; ++ni)
                acc[mi][ni] = (floatx4){0.f, 0.f, 0.f, 0.f};

        // ---- S. serial staging phase: rows 2st+6, 2st+7 into spare slots.
        // Spare slots are disjoint from this step's active slots; the
        // end-of-step barrier orders these writes vs next step's reads.
        if (st < STEPS - 1) {
            #pragma unroll 1
            for (int k = 0; k < 3; ++k) {
                int it = tid + 256 * k;
                if (it < 2 * NIT) {
                    int second = (it >= NIT);
                    int rem = it - (second ? NIT : 0);
                    int j   = 2 * st + 6 + second;
                    int w4  = rem >> 3;
                    int q   = rem & 7;
                    int ih  = ihbase + 2 * j;
                    int iw0 = iwbase + 4 * w4;
                    float4 m0 = {0,0,0,0}, m1 = {0,0,0,0}, m2 = {0,0,0,0}, m3 = {0,0,0,0};
                    if ((unsigned)ih < HH && (unsigned)iw0 < WW) {
                        const float* p = xb + (size_t)(4 * q) * cstr + (size_t)ih * WW + iw0;
                        m0 = *(const float4*)(p);
                        m1 = *(const float4*)(p + cstr);
                        m2 = *(const float4*)(p + 2 * cstr);
                        m3 = *(const float4*)(p + 3 * cstr);
                    }
                    u16* dst = s + (j & 7) * SLOT_STRIDE + (q >> 1) * OCT_STRIDE + (q & 1) * 4;
                    const float* f0 = (const float*)&m0; const float* f1 = (const float*)&m1;
                    const float* f2 = (const float*)&m2; const float* f3 = (const float*)&m3;
                    #pragma unroll
                    for (int jj = 0; jj < 4; ++jj) {
                        u32 lo = (u32)f2bf(f0[jj]) | ((u32)f2bf(f1[jj]) << 16);
                        u32 hi = (u32)f2bf(f2[jj]) | ((u32)f2bf(f3[jj]) << 16);
                        *(uint2*)(dst + (4 * w4 + jj) * 8) = make_uint2(lo, hi);
                    }
                }
            }
        }

        // ---- B. flat 45-tap ping-pong pipeline, running A pointer ----
        {
            const int js = 2 * st;
            const u16* bsl0 = s + ((js + wo + 0) & 7) * SLOT_STRIDE + bfixed;
            const u16* bsl1 = s + ((js + wo + 1) & 7) * SLOT_STRIDE + bfixed;
            const u16* bsl2 = s + ((js + wo + 2) & 7) * SLOT_STRIDE + bfixed;
            const u16* bsl3 = s + ((js + wo + 3) & 7) * SLOT_STRIDE + bfixed;
            const u16* bsl4 = s + ((js + wo + 4) & 7) * SLOT_STRIDE + bfixed;

            short8 ax0, ax1, ax2, ax3, ay0, ay1, ay2, ay3;
            short8 bx0, bx1, bx2, bx3, by0, by1, by2, by3;

            const u16* ap = abase0;             // running tap pointer
            LOADA(ax0, ax1, ax2, ax3, ap);      // tap 0
            LOADB(bx0, bx1, bx2, bx3, bsl0, 0); // tap 0

            // body t computes tap t, prefetches tap t+1 (args = t+1 coords)
            TAPX(bsl0, 1); TAPY(bsl0, 2); TAPX(bsl0, 3); TAPY(bsl0, 4);
            TAPX(bsl0, 5); TAPY(bsl0, 6); TAPX(bsl0, 7); TAPY(bsl0, 8);
            TAPX(bsl1, 0); TAPY(bsl1, 1); TAPX(bsl1, 2); TAPY(bsl1, 3);
            TAPX(bsl1, 4); TAPY(bsl1, 5); TAPX(bsl1, 6); TAPY(bsl1, 7);
            TAPX(bsl1, 8); TAPY(bsl2, 0); TAPX(bsl2, 1); TAPY(bsl2, 2);
            TAPX(bsl2, 3); TAPY(bsl2, 4); TAPX(bsl2, 5); TAPY(bsl2, 6);
            TAPX(bsl2, 7); TAPY(bsl2, 8); TAPX(bsl3, 0); TAPY(bsl3, 1);
            TAPX(bsl3, 2); TAPY(bsl3, 3); TAPX(bsl3, 4); TAPY(bsl3, 5);
            TAPX(bsl3, 6); TAPY(bsl3, 7); TAPX(bsl3, 8); TAPY(bsl4, 0);
            TAPX(bsl4, 1); TAPY(bsl4, 2); TAPX(bsl4, 3); TAPY(bsl4, 4);
            TAPX(bsl4, 5); TAPY(bsl4, 6); TAPX(bsl4, 7); TAPY(bsl4, 8);
            // t=44 (even -> X buffers, loaded by the last TAPY):
            MFMA16(ax0, ax1, ax2, ax3, bx0, bx1, bx2, bx3);
        }

        __syncthreads();

        // ---- D. store this step's outputs ----
        const int oh = oh0 + 4 * st + 2 * wo;
        if (oh < OH) {
            #pragma unroll
            for (int ni = 0; ni < 4; ++ni) {
                const int posb = w0 + 64 * wp + 16 * ni;
                if (posb < OW) {
                    const int pos = posb + li;
                    #pragma unroll
                    for (int mi = 0; mi < 4; ++mi) {
                        float* op = out + (((size_t)(b * COUT + 16 * mi + 4 * h) * OH + oh) * OW) + pos;
                        #pragma unroll
                        for (int reg = 0; reg < 4; ++reg)
                            op[(size_t)reg * OH * OW] = acc[mi][ni][reg];
                    }
                }
            }
        }
    }
#undef LOADA
#undef LOADB
#undef MFMA16
#undef TAPX
#undef TAPY
}

extern "C" void kernel_launch(void* const* d_in, const int* in_sizes, int n_in,
                              void* d_out, int out_size, void* d_ws, size_t ws_size,
                              hipStream_t stream) {
    const float* x = (const float*)d_in[0];
    const float* w = (const float*)d_in[1];
    float* out = (float*)d_out;
    u16* wrep = (u16*)d_ws;  // 45*64*32*2 = 184320 B

    repack_w_k<<<(NTAP * COUT * CIN + 255) / 256, 256, 0, stream>>>(w, wrep);

    dim3 grid(8 /* wt(4) x parity(2) */, 8 /* chunks */, 8 /* batch */);
    conv_ring<<<grid, dim3(256), 0, stream>>>(x, wrep, out);
}

// Round 9
// 467.514 us; speedup vs baseline: 3.6171x; 3.6171x over previous
//
#include <hip/hip_runtime.h>

// Dilated conv2d as implicit GEMM, parity-ring edition, round 9:
// EXACT round-3 structure (proven 570 us, VGPR 100, no spill), two edits:
//  1. kw loop unroll 3 -> full 9: scheduling region = one r-row (144 MFMA,
//     36 A-loads, 36 B-reads) so A-latency is exposed once per r, not 3x.
//     (Unroll-region/spill curve: 16-MFMA ok, 48 ok, 720 spills; probing 144.)
//  2. T5 s_setprio around the MFMA cluster (2 drifting block domains per CU).

#define CIN 32
#define HH 512
#define WW 512
#define COUT 64
#define OH 508
#define OW 496
#define KH 5
#define KW 9

#define WTILE 128
#define SW 152              // staged width: 128 + 24 halo (origin iw = w0-4)
#define OCT_STRIDE 1224     // SW*8 + 8 elts = 2448B (16B-aligned, banks spread)
#define SLOT_STRIDE 4896    // 4 * OCT_STRIDE elts = 9792B per row-slab
#define NSLOT 8             // ring: 6 active + 2 prefetch (78336 B total)
#define NIT 304             // staging items per row: (SW/4)*8
#define STEPS 16            // 2 oh rows per step -> 32 same-parity oh per block

typedef short short8 __attribute__((ext_vector_type(8)));
typedef float floatx4 __attribute__((ext_vector_type(4)));
typedef unsigned short u16;
typedef unsigned int u32;

__device__ __forceinline__ u16 f2bf(float f) {  // RNE f32->bf16
    u32 u = __float_as_uint(f);
    return (u16)((u + 0x7fffu + ((u >> 16) & 1u)) >> 16);
}

__global__ void repack_w_k(const float* __restrict__ w, u16* __restrict__ wr) {
    int idx = blockIdx.x * 256 + threadIdx.x;
    if (idx >= KH * KW * COUT * CIN) return;
    int tap = idx / (COUT * CIN);
    int rem = idx - tap * (COUT * CIN);
    int co = rem / CIN;
    int ci = rem - co * CIN;
    int r  = tap / KW;
    int kw = tap - r * KW;
    wr[idx] = f2bf(w[((co * CIN + ci) * KH + r) * KW + kw]);
}

__global__ __launch_bounds__(256, 2)
void conv_ring(const float* __restrict__ x, const u16* __restrict__ wrep,
               float* __restrict__ out) {
    __shared__ u16 s[NSLOT * SLOT_STRIDE];  // 78336 B -> 2 blocks/CU

    const int bx     = blockIdx.x;          // 0..7: wt(2b) | parity(1b)
    const int wt     = bx & 3;
    const int parity = bx >> 2;
    const int chunk  = blockIdx.y;          // 0..7
    const int b      = blockIdx.z;          // 0..7
    const int w0     = wt * WTILE;
    const int oh0    = parity + 64 * chunk;
    const int ihbase = oh0 - 2;
    const int iwbase = w0 - 4;

    const int tid  = threadIdx.x;
    const int lane = tid & 63;
    const int wave = tid >> 6;
    const int wp   = wave & 1;   // pos half (64)
    const int wo   = wave >> 1;  // which of the 2 oh rows this step
    const int li   = lane & 15;
    const int h    = lane >> 4;

    const size_t cstr = (size_t)HH * WW;    // x channel stride
    const float* xb = x + (size_t)b * CIN * cstr;

    // ---------------- prologue: stage rows j = 0..5 ----------------
    for (int it = tid; it < 6 * NIT; it += 256) {
        int j   = it / NIT;
        int rem = it - j * NIT;
        int w4  = rem >> 3;
        int q   = rem & 7;      // cin quad: cin = 4q..4q+3
        int ih  = ihbase + 2 * j;
        int iw0 = iwbase + 4 * w4;
        float4 m0 = {0,0,0,0}, m1 = {0,0,0,0}, m2 = {0,0,0,0}, m3 = {0,0,0,0};
        if ((unsigned)ih < HH && (unsigned)iw0 < WW) {
            const float* p = xb + (size_t)(4 * q) * cstr + (size_t)ih * WW + iw0;
            m0 = *(const float4*)(p);
            m1 = *(const float4*)(p + cstr);
            m2 = *(const float4*)(p + 2 * cstr);
            m3 = *(const float4*)(p + 3 * cstr);
        }
        u16* dst = s + (j & 7) * SLOT_STRIDE + (q >> 1) * OCT_STRIDE + (q & 1) * 4;
        const float* f0 = (const float*)&m0; const float* f1 = (const float*)&m1;
        const float* f2 = (const float*)&m2; const float* f3 = (const float*)&m3;
        #pragma unroll
        for (int jj = 0; jj < 4; ++jj) {
            u32 lo = (u32)f2bf(f0[jj]) | ((u32)f2bf(f1[jj]) << 16);
            u32 hi = (u32)f2bf(f2[jj]) | ((u32)f2bf(f3[jj]) << 16);
            *(uint2*)(dst + (4 * w4 + jj) * 8) = make_uint2(lo, hi);
        }
    }
    __syncthreads();

    const u16* abase0 = wrep + li * CIN + 8 * h;
    const int  bfixed = h * OCT_STRIDE + (64 * wp + li) * 8;

    floatx4 acc[4][4];

    #pragma unroll 1
    for (int st = 0; st < STEPS; ++st) {
        #pragma unroll
        for (int mi = 0; mi < 4; ++mi)
            #pragma unroll
            for (int ni = 0; ni < 4; ++ni)
                acc[mi][ni] = (floatx4){0.f, 0.f, 0.f, 0.f};

        // ---- A. issue prefetch loads for rows 2st+6, 2st+7 (regs) ----
        const bool doPref = (st < STEPS - 1);
        float4 pv[3][4];
        #pragma unroll
        for (int k = 0; k < 3; ++k) {
            #pragma unroll
            for (int c = 0; c < 4; ++c) pv[k][c] = (float4){0,0,0,0};
            int it = tid + 256 * k;
            if (doPref && it < 2 * NIT) {
                int second = (it >= NIT);
                int rem = it - (second ? NIT : 0);
                int j   = 2 * st + 6 + second;
                int w4  = rem >> 3;
                int q   = rem & 7;
                int ih  = ihbase + 2 * j;
                int iw0 = iwbase + 4 * w4;
                if ((unsigned)ih < HH && (unsigned)iw0 < WW) {
                    const float* p = xb + (size_t)(4 * q) * cstr + (size_t)ih * WW + iw0;
                    pv[k][0] = *(const float4*)(p);
                    pv[k][1] = *(const float4*)(p + cstr);
                    pv[k][2] = *(const float4*)(p + 2 * cstr);
                    pv[k][3] = *(const float4*)(p + 3 * cstr);
                }
            }
        }

        // ---- B. 45 taps: r loop serial, kw loop FULLY unrolled (144-MFMA
        //      region: 36 A-loads + 36 B-reads schedulable across the row) ----
        const int js = 2 * st;
        #pragma unroll 1
        for (int r = 0; r < KH; ++r) {
            const u16* bb = s + ((js + wo + r) & 7) * SLOT_STRIDE + bfixed;
            const u16* ab = abase0 + (size_t)(r * KW) * (COUT * CIN);
            #pragma unroll
            for (int kw = 0; kw < KW; ++kw) {
                short8 af[4], bf_[4];
                #pragma unroll
                for (int mi = 0; mi < 4; ++mi)
                    af[mi] = *(const short8*)(ab + (kw * COUT + mi * 16) * CIN);
                #pragma unroll
                for (int ni = 0; ni < 4; ++ni)
                    bf_[ni] = *(const short8*)(bb + (16 * ni + 3 * kw) * 8);
                __builtin_amdgcn_s_setprio(1);
                #pragma unroll
                for (int mi = 0; mi < 4; ++mi)
                    #pragma unroll
                    for (int ni = 0; ni < 4; ++ni)
                        acc[mi][ni] = __builtin_amdgcn_mfma_f32_16x16x32_bf16(
                            af[mi], bf_[ni], acc[mi][ni], 0, 0, 0);
                __builtin_amdgcn_s_setprio(0);
            }
        }

        // ---- C. convert + ds_write the prefetched rows into ring ----
        if (doPref) {
            #pragma unroll
            for (int k = 0; k < 3; ++k) {
                int it = tid + 256 * k;
                if (it < 2 * NIT) {
                    int second = (it >= NIT);
                    int rem = it - (second ? NIT : 0);
                    int j   = 2 * st + 6 + second;
                    int w4  = rem >> 3;
                    int q   = rem & 7;
                    u16* dst = s + (j & 7) * SLOT_STRIDE + (q >> 1) * OCT_STRIDE + (q & 1) * 4;
                    const float* f0 = (const float*)&pv[k][0];
                    const float* f1 = (const float*)&pv[k][1];
                    const float* f2 = (const float*)&pv[k][2];
                    const float* f3 = (const float*)&pv[k][3];
                    #pragma unroll
                    for (int jj = 0; jj < 4; ++jj) {
                        u32 lo = (u32)f2bf(f0[jj]) | ((u32)f2bf(f1[jj]) << 16);
                        u32 hi = (u32)f2bf(f2[jj]) | ((u32)f2bf(f3[jj]) << 16);
                        *(uint2*)(dst + (4 * w4 + jj) * 8) = make_uint2(lo, hi);
                    }
                }
            }
        }
        __syncthreads();

        // ---- D. store this step's outputs ----
        const int oh = oh0 + 4 * st + 2 * wo;
        if (oh < OH) {
            #pragma unroll
            for (int ni = 0; ni < 4; ++ni) {
                const int posb = w0 + 64 * wp + 16 * ni;
                if (posb < OW) {
                    const int pos = posb + li;
                    #pragma unroll
                    for (int mi = 0; mi < 4; ++mi) {
                        float* op = out + (((size_t)(b * COUT + 16 * mi + 4 * h) * OH + oh) * OW) + pos;
                        #pragma unroll
                        for (int reg = 0; reg < 4; ++reg)
                            op[(size_t)reg * OH * OW] = acc[mi][ni][reg];
                    }
                }
            }
        }
    }
}

extern "C" void kernel_launch(void* const* d_in, const int* in_sizes, int n_in,
                              void* d_out, int out_size, void* d_ws, size_t ws_size,
                              hipStream_t stream) {
    const float* x = (const float*)d_in[0];
    const float* w = (const float*)d_in[1];
    float* out = (float*)d_out;
    u16* wrep = (u16*)d_ws;  // 45*64*32*2 = 184320 B

    repack_w_k<<<(KH * KW * COUT * CIN + 255) / 256, 256, 0, stream>>>(w, wrep);

    dim3 grid(8 /* wt(4) x parity(2) */, 8 /* chunks */, 8 /* batch */);
    conv_ring<<<grid, dim3(256), 0, stream>>>(x, wrep, out);
}